// Round 8
// baseline (893.707 us; speedup 1.0000x reference)
//
#include <hip/hip_runtime.h>
#include <cstdio>

#define NHEAD 12
#define NPIX 784
#define NBATCH 16
#define CDIM 384
// fused (fallback) params
#define TQF 6
#define SLOTS 8
#define MPITCH 786
#define IPITCH 12
// split-path params
#define TQ 2          // query rows per conv block (37.7 KB LDS -> 4 blocks/CU)
#define SROW 9432     // S row stride in u16 (786*12)
#define LROW 9424     // LDS logits row pitch in u16
#define CW 8          // conv_fused waves per block (512 threads; >512 doesn't pack, round 7)

typedef __bf16 bf16x8 __attribute__((ext_vector_type(8)));
typedef float f32x4 __attribute__((ext_vector_type(4)));
typedef unsigned short u16;
typedef unsigned short u16x4 __attribute__((ext_vector_type(4)));
typedef unsigned short u16x8 __attribute__((ext_vector_type(8)));

__device__ __forceinline__ float b2f(u16 u){
  unsigned int x = ((unsigned int)u) << 16;
  float f; __builtin_memcpy(&f, &x, 4); return f;
}
__device__ __forceinline__ u16 f2b(float f){
  unsigned int x; __builtin_memcpy(&x, &f, 4);
  unsigned int r = (x + 0x7FFFu + ((x >> 16) & 1u)) >> 16;
  return (u16)r;
}
__device__ __forceinline__ f32x4 mfma_bf16(u16x8 a, u16x8 b, f32x4 c){
  return __builtin_amdgcn_mfma_f32_16x16x32_bf16(
      __builtin_bit_cast(bf16x8, a), __builtin_bit_cast(bf16x8, b), c, 0, 0, 0);
}
__device__ __forceinline__ u16x8 ldfrag12(const u16* S, int base, int g){
  u16x8 r = (u16x8)0;
  if (g == 0){
    u16x4 lo = *(const u16x4*)(S + base);
    u16x4 hi = *(const u16x4*)(S + base + 4);
    r[0]=lo[0]; r[1]=lo[1]; r[2]=lo[2]; r[3]=lo[3];
    r[4]=hi[0]; r[5]=hi[1]; r[6]=hi[2]; r[7]=hi[3];
  } else if (g == 1){
    u16x4 lo = *(const u16x4*)(S + base + 8);
    r[0]=lo[0]; r[1]=lo[1]; r[2]=lo[2]; r[3]=lo[3];
  }
  return r;
}

// ---------------- prep: weights ----------------
__global__ void prep_w(const float* Wq, const float* bq, const float* Wkv, const float* bkv,
                       const float* Wo, u16* Wall, float* ball, u16* Wo_bf){
  int idx = blockIdx.x * 256 + threadIdx.x;
  const float scale = 0.17677669529663687f; // 1/sqrt(32)
  const int t1 = 1152 * 384;
  if (idx < t1){
    float v = (idx < 384*384) ? Wq[idx] * scale : Wkv[idx - 384*384];
    Wall[idx] = f2b(v);
  } else if (idx < t1 + 384*384){
    Wo_bf[idx - t1] = f2b(Wo[idx - t1]);
  } else if (idx < t1 + 384*384 + 1152){
    int o = idx - t1 - 384*384;
    ball[o] = (o < 384) ? bq[o] * scale : bkv[o - 384];
  }
}

__global__ void zfill(u16* p, int n){
  int idx = blockIdx.x * 512 + threadIdx.x;
  if (idx < n) p[idx] = 0;
}

// ---------------- prep: x transpose to [b][n][c] bf16 ----------------
__global__ void prep_xt(const float* x, u16* xT){
  __shared__ float tile[32][33];
  int bid = blockIdx.x;
  int nt = bid % 25; int ct = (bid / 25) % 12; int b = bid / (25 * 12);
  int n0 = nt * 32, c0 = ct * 32;
  int lt = threadIdx.x;
  int ln = lt & 31, lr = lt >> 5;
  #pragma unroll
  for (int k = 0; k < 4; k++){
    int c = lr + k * 8;
    int n = n0 + ln;
    float v = (n < NPIX) ? x[(b * CDIM + c0 + c) * NPIX + n] : 0.f;
    tile[c][ln] = v;
  }
  __syncthreads();
  #pragma unroll
  for (int k = 0; k < 4; k++){
    int wn = lr + k * 8;
    int n = n0 + wn;
    if (n < NPIX) xT[(b * NPIX + n) * CDIM + c0 + ln] = f2b(tile[ln][wn]);
  }
}

// ---------------- prep: bias table [n][m][12] = rpb[rel]+bre ----------------
__global__ void prep_bias(const int* rel, const float* rpb, const float* bre, u16* biasC){
  int idx = blockIdx.x * 256 + threadIdx.x;
  if (idx >= NPIX * NPIX) return;
  int ri = rel[idx];
  u16x4 v[3];
  #pragma unroll
  for (int h = 0; h < 12; h++){
    float val = rpb[ri * 12 + h] + bre[h];
    v[h >> 2][h & 3] = f2b(val);
  }
  u16x4* dst = (u16x4*)(biasC + idx * 12);
  dst[0] = v[0]; dst[1] = v[1]; dst[2] = v[2];
}

// ---------------- K1: QKV projection GEMM ----------------
__global__ __launch_bounds__(256) void qkv_gemm(const u16* Wall, const float* ball, const u16* xT,
                                                u16* Qs, u16* Kb, u16* Vt){
  int bid = blockIdx.x;
  int nt = bid % 7; int ot = (bid / 7) % 18; int b = bid / 126;
  int o0 = ot * 64, n0 = nt * 112;
  int lane = threadIdx.x & 63, w = threadIdx.x >> 6;
  int col = lane & 15, g = lane >> 4;
  int orow = o0 + w * 16;
  f32x4 acc[7];
  #pragma unroll
  for (int i = 0; i < 7; i++) acc[i] = (f32x4)0.f;
  for (int ks = 0; ks < 12; ks++){
    int c0 = ks * 32;
    u16x8 a = *(const u16x8*)(Wall + (orow + col) * CDIM + c0 + 8 * g);
    #pragma unroll
    for (int t = 0; t < 7; t++){
      int n = n0 + t * 16 + col;
      u16x8 bb = *(const u16x8*)(xT + (b * NPIX + n) * CDIM + c0 + 8 * g);
      acc[t] = mfma_bf16(a, bb, acc[t]);
    }
  }
  #pragma unroll
  for (int t = 0; t < 7; t++){
    int n = n0 + t * 16 + col;
    #pragma unroll
    for (int r = 0; r < 4; r++){
      int o = orow + 4 * g + r;
      u16 hv = f2b(acc[t][r] + ball[o]);
      if (o < 384){
        int h = o >> 5, d = o & 31;
        Qs[((b * 12 + h) * NPIX + n) * 32 + d] = hv;
      } else if (o < 768){
        int oo = o - 384; int h = oo >> 5, d = oo & 31;
        Kb[((b * 12 + h) * NPIX + n) * 32 + d] = hv;
      } else {
        int oo = o - 768; int h = oo >> 5, d = oo & 31;
        Vt[((b * 12 + h) * 32 + d) * NPIX + n] = hv;
      }
    }
  }
}

// ---------------- K2a: S = Q K^T, layout [bg][n][786][12] bf16 (m padded +-1) ----------------
__global__ __launch_bounds__(512) void s_gemm(const u16* Qs, const u16* Kb, u16* S, int b0){
  int bid = blockIdx.x;
  int nt = bid % 49; int bg = bid / 49;
  int b = b0 + bg;
  int n0 = nt * 16;
  int tid = threadIdx.x;
  int lane = tid & 63, wid = tid >> 6;
  int col = lane & 15, g = lane >> 4;
  u16* Sb = S + (size_t)bg * NPIX * SROW;
  // zero pad columns mp=0 and mp=785 for this n-strip
  for (int idx = tid; idx < 16 * 24; idx += 512){
    int r = idx / 24, c = idx % 24;
    int mp = (c < 12) ? 0 : 785;
    Sb[(size_t)(n0 + r) * SROW + mp * 12 + (c % 12)] = 0;
  }
  // hoist the 12 Q fragments (independent of mt)
  u16x8 af[12];
  #pragma unroll
  for (int h = 0; h < 12; h++)
    af[h] = *(const u16x8*)(Qs + ((size_t)(b * 12 + h) * NPIX + n0 + col) * 32 + 8 * g);
  for (int mt = wid; mt < 49; mt += 8){
    int m0 = mt * 16;
    u16x4 res[4][3];   // [r][word-of-3 u16x4] = 12 heads per (n,m)
    #pragma unroll
    for (int h = 0; h < 12; h++){
      u16x8 bb = *(const u16x8*)(Kb + ((size_t)(b * 12 + h) * NPIX + m0 + col) * 32 + 8 * g);
      f32x4 acc = mfma_bf16(af[h], bb, (f32x4)0.f);
      #pragma unroll
      for (int r = 0; r < 4; r++) res[r][h >> 2][h & 3] = f2b(acc[r]);
    }
    #pragma unroll
    for (int r = 0; r < 4; r++){
      size_t base = (size_t)(n0 + 4 * g + r) * SROW + (size_t)(1 + m0 + col) * 12;
      *(u16x4*)(Sb + base)     = res[r][0];
      *(u16x4*)(Sb + base + 4) = res[r][1];
      *(u16x4*)(Sb + base + 8) = res[r][2];
    }
  }
}

// ---------------- K2b: conv+bias+softmax+headmix+PV, TQ=2 rows, 37.7 KB LDS ----------------
__global__ __launch_bounds__(512, 4) void conv_fused(const u16* S, const u16* zrow,
        const u16* biasC, const float* Wre, const float* Wrp, const float* brp,
        const u16* Vt, u16* O, int b0){
  extern __shared__ u16 L[];   // [TQ][LROW]
  int bid = blockIdx.x;
  int nt = bid % 392; int bg = bid / 392;
  int b = b0 + bg;
  int n0 = nt * TQ;
  int tid = threadIdx.x;
  int lane = tid & 63, wid = tid >> 6;
  int col = lane & 15, g = lane >> 4;
  const u16* Sb = S + (size_t)bg * NPIX * SROW;

  // conv weight fragments (2-tap K=24 pack: wf1: k<12 -> dx=0, k in [12,24) -> dx=1; wf2: k<12 -> dx=2)
  u16x8 wf1[3], wf2[3];
  #pragma unroll
  for (int dy = 0; dy < 3; dy++){
    u16x8 f1 = (u16x8)0, f2 = (u16x8)0;
    #pragma unroll
    for (int jj = 0; jj < 8; jj++){
      int k = 8 * g + jj;
      float v1 = 0.f, v2 = 0.f;
      if (col < 12){
        if (k < 12){
          v1 = Wre[((col * 12 + k) * 3 + dy) * 3 + 0];
          v2 = Wre[((col * 12 + k) * 3 + dy) * 3 + 2];
        } else if (k < 24){
          int i = k - 12;
          v1 = Wre[((col * 12 + i) * 3 + dy) * 3 + 1];
        }
      }
      f1[jj] = f2b(v1); f2[jj] = f2b(v2);
    }
    wf1[dy] = f1; wf2[dy] = f2;
  }

  // phase 1: conv + identity + bias -> logits in LDS, 4-row reuse per m-tile
  for (int mt = wid; mt < 49; mt += CW){
    int m0 = mt * 16;
    const u16* rp[TQ + 2];
    #pragma unroll
    for (int rr = 0; rr < TQ + 2; rr++){
      int r = n0 - 1 + rr;
      rp[rr] = (r >= 0 && r < NPIX) ? Sb + (size_t)r * SROW : zrow;
    }
    u16x8 fA[TQ + 2], fB[TQ + 2];
    #pragma unroll
    for (int rr = 0; rr < TQ + 2; rr++){
      fA[rr] = (g < 3) ? *(const u16x8*)(rp[rr] + (m0 + col) * 12 + 8 * g) : (u16x8)0;
      fB[rr] = (g < 2) ? *(const u16x8*)(rp[rr] + (m0 + col + 2) * 12 + 8 * g) : (u16x8)0;
    }
    f32x4 acc[TQ];
    #pragma unroll
    for (int n = 0; n < TQ; n++) acc[n] = (f32x4)0.f;
    #pragma unroll
    for (int dy = 0; dy < 3; dy++){
      #pragma unroll
      for (int n = 0; n < TQ; n++){
        acc[n] = mfma_bf16(wf1[dy], fA[n + dy], acc[n]);
        acc[n] = mfma_bf16(wf2[dy], fB[n + dy], acc[n]);
      }
    }
    if (g < 3){
      #pragma unroll
      for (int n = 0; n < TQ; n++){
        u16x4 idv = *(const u16x4*)(rp[n + 1] + (m0 + col + 1) * 12 + 4 * g);
        u16x4 bv  = *(const u16x4*)(biasC + ((size_t)(n0 + n) * NPIX + m0 + col) * 12 + 4 * g);
        u16x4 wv;
        #pragma unroll
        for (int r = 0; r < 4; r++) wv[r] = f2b(acc[n][r] + b2f(idv[r]) + b2f(bv[r]));
        *(u16x4*)(L + n * LROW + (m0 + col) * 12 + 4 * g) = wv;
      }
    }
  }
  __syncthreads();

  // phase 2: softmax per row, 4 heads per job (vectorized u16x4 LDS access)
  for (int job = wid; job < TQ * 3; job += CW){
    int row = job / 3, hg = job % 3;
    f32x4 vals[13];
    f32x4 mx;
    #pragma unroll
    for (int c = 0; c < 4; c++) mx[c] = -1e30f;
    #pragma unroll
    for (int tt = 0; tt < 13; tt++){
      int m = lane + 64 * tt;
      f32x4 v;
      if (m < NPIX){
        u16x4 lv = *(const u16x4*)(L + row * LROW + m * 12 + 4 * hg);
        #pragma unroll
        for (int c = 0; c < 4; c++) v[c] = b2f(lv[c]);
      } else {
        #pragma unroll
        for (int c = 0; c < 4; c++) v[c] = -1e30f;
      }
      vals[tt] = v;
      #pragma unroll
      for (int c = 0; c < 4; c++) mx[c] = fmaxf(mx[c], v[c]);
    }
    #pragma unroll
    for (int o = 32; o > 0; o >>= 1){
      #pragma unroll
      for (int c = 0; c < 4; c++) mx[c] = fmaxf(mx[c], __shfl_xor(mx[c], o));
    }
    f32x4 sum = (f32x4)0.f;
    #pragma unroll
    for (int tt = 0; tt < 13; tt++){
      int m = lane + 64 * tt;
      f32x4 e;
      if (m < NPIX){
        #pragma unroll
        for (int c = 0; c < 4; c++) e[c] = __expf(vals[tt][c] - mx[c]);
      } else {
        e = (f32x4)0.f;
      }
      vals[tt] = e;
      #pragma unroll
      for (int c = 0; c < 4; c++) sum[c] += e[c];
    }
    #pragma unroll
    for (int o = 32; o > 0; o >>= 1){
      #pragma unroll
      for (int c = 0; c < 4; c++) sum[c] += __shfl_xor(sum[c], o);
    }
    f32x4 inv;
    #pragma unroll
    for (int c = 0; c < 4; c++) inv[c] = 1.f / sum[c];
    #pragma unroll
    for (int tt = 0; tt < 13; tt++){
      int m = lane + 64 * tt;
      if (m < NPIX){
        u16x4 wv;
        #pragma unroll
        for (int c = 0; c < 4; c++) wv[c] = f2b(vals[tt][c] * inv[c]);
        *(u16x4*)(L + row * LROW + m * 12 + 4 * hg) = wv;
      }
    }
  }
  __syncthreads();

  // phase 3: P' = P + Wrp@P + brp, in place (exact f32 identity add)
  u16x8 pfrag = (u16x8)0;
  #pragma unroll
  for (int jj = 0; jj < 8; jj++){
    int k = 8 * g + jj;
    pfrag[jj] = f2b((col < 12 && k < 12) ? Wrp[col * 12 + k] : 0.f);
  }
  float brpv[4];
  #pragma unroll
  for (int r = 0; r < 4; r++){ int o = 4 * g + r; brpv[r] = (o < 12) ? brp[o] : 0.f; }
  for (int job = wid; job < TQ * 49; job += CW){
    int row = job / 49, mt = job % 49;
    int m0 = mt * 16;
    int base = row * LROW + (m0 + col) * 12;
    u16x8 bf = ldfrag12(L, base, g);
    f32x4 d = mfma_bf16(pfrag, bf, (f32x4)0.f);
    u16x4 idv = *(const u16x4*)(L + base + 4 * g);
    if (g < 3){
      u16x4 wv;
      #pragma unroll
      for (int r = 0; r < 4; r++) wv[r] = f2b(d[r] + b2f(idv[r]) + brpv[r]);
      *(u16x4*)(L + base + 4 * g) = wv;
    }
  }
  __syncthreads();

  // phase 4: PV -> O[b][n][h*32+d]; af loaded once per h, shared by both d-halves
  for (int job = wid; job < 12; job += CW){
    int h = job;
    f32x4 acc0 = (f32x4)0.f, acc1 = (f32x4)0.f;
    for (int ks = 0; ks < 25; ks++){
      int m0 = ks * 32;
      u16x8 af = (u16x8)0;
      if (col < TQ){
        #pragma unroll
        for (int jj = 0; jj < 8; jj++){
          int m = m0 + 8 * g + jj;
          if (m < NPIX) af[jj] = L[col * LROW + m * 12 + h];
        }
      }
      u16x8 bv0 = (u16x8)0, bv1 = (u16x8)0;
      if (m0 + 8 * g < NPIX){
        bv0 = *(const u16x8*)(Vt + ((size_t)(b * 12 + h) * 32 + col) * NPIX + m0 + 8 * g);
        bv1 = *(const u16x8*)(Vt + ((size_t)(b * 12 + h) * 32 + 16 + col) * NPIX + m0 + 8 * g);
      }
      acc0 = mfma_bf16(af, bv0, acc0);
      acc1 = mfma_bf16(af, bv1, acc1);
    }
    if (g == 0){
      size_t ob = (size_t)(b * NPIX + n0) * CDIM + h * 32 + col;
      #pragma unroll
      for (int r = 0; r < TQ; r++){
        O[ob + (size_t)r * CDIM]      = f2b(acc0[r]);
        O[ob + (size_t)r * CDIM + 16] = f2b(acc1[r]);
      }
    }
  }
}

// ---------------- fallback fused kernel (round-1, proven) ----------------
__global__ __launch_bounds__(512) void attn_fused(const u16* Qs, const u16* Kb, const u16* Vt,
        const u16* biasC, const float* Wre, const float* Wrp, const float* brp, u16* O){
  extern __shared__ u16 S[];
  int j = blockIdx.x;
  int rb = j & 7, q = j >> 3;
  int b = rb + 8 * (q & 1);
  int t = q >> 1;
  int n0 = t * TQF;
  int nvalid = min(TQF, NPIX - n0);
  int tid = threadIdx.x;
  int lane = tid & 63, wid = tid >> 6;
  int col = lane & 15, g = lane >> 4;

  for (int idx = tid; idx < SLOTS * 2 * 12; idx += 512){
    int slot = idx / 24; int rem = idx % 24; int cs = rem / 12; int i = rem % 12;
    int mcol = cs ? (MPITCH - 1) : 0;
    S[(slot * MPITCH + mcol) * IPITCH + i] = 0;
  }
  if (tid < 16) S[SLOTS * MPITCH * IPITCH + tid] = 0;
  __syncthreads();

  for (int job = wid; job < 147; job += 8){
    int hg = job / 49, mt = job % 49;
    int h0 = hg * 4, m0 = mt * 16;
    f32x4 acc[4];
    #pragma unroll
    for (int hh = 0; hh < 4; hh++){
      int h = h0 + hh;
      u16x8 a = *(const u16x8*)(Kb + ((b * 12 + h) * NPIX + m0 + col) * 32 + 8 * g);
      int nn = n0 - 1 + col;
      u16x8 bb = (u16x8)0;
      if (col < 8 && nn >= 0 && nn < NPIX)
        bb = *(const u16x8*)(Qs + ((b * 12 + h) * NPIX + nn) * 32 + 8 * g);
      acc[hh] = mfma_bf16(a, bb, (f32x4)0.f);
    }
    if (col < 8){
      #pragma unroll
      for (int r = 0; r < 4; r++){
        int m = m0 + 4 * g + r;
        u16x4 wv;
        #pragma unroll
        for (int hh = 0; hh < 4; hh++) wv[hh] = f2b(acc[hh][r]);
        *(u16x4*)(S + (col * MPITCH + 1 + m) * IPITCH + h0) = wv;
      }
    }
  }
  __syncthreads();

  u16x8 wfrag[9];
  #pragma unroll
  for (int dy = 0; dy < 3; dy++)
  #pragma unroll
  for (int dx = 0; dx < 3; dx++){
    u16x8 f;
    #pragma unroll
    for (int jj = 0; jj < 8; jj++){
      int k = 8 * g + jj;
      float v = (col < 12 && k < 12) ? Wre[(col * 12 + k) * 9 + dy * 3 + dx] : 0.f;
      f[jj] = f2b(v);
    }
    wfrag[dy * 3 + dx] = f;
  }

  for (int n = 0; n < TQF; n++){
    bool rv = (n < nvalid);
    int ngl = n0 + n;
    f32x4 accv[7];
    if (rv){
      #pragma unroll
      for (int it = 0; it < 7; it++){
        int mt = wid + it * 8;
        if (mt < 49){
          int m0 = mt * 16;
          f32x4 a = (f32x4)0.f;
          #pragma unroll
          for (int dy = 0; dy < 3; dy++){
            int slot = n + dy;
            #pragma unroll
            for (int dx = 0; dx < 3; dx++){
              int base = (slot * MPITCH + (m0 + col + dx)) * IPITCH;
              u16x8 bf = ldfrag12(S, base, g);
              a = mfma_bf16(wfrag[dy * 3 + dx], bf, a);
            }
          }
          u16x4 idv = *(const u16x4*)(S + ((n + 1) * MPITCH + 1 + m0 + col) * IPITCH + 4 * g);
          u16x4 bv  = *(const u16x4*)(biasC + (ngl * NPIX + m0 + col) * 12 + 4 * g);
          f32x4 res;
          #pragma unroll
          for (int r = 0; r < 4; r++) res[r] = a[r] + b2f(idv[r]) + b2f(bv[r]);
          accv[it] = res;
        }
      }
    }
    __syncthreads();
    if (rv){
      #pragma unroll
      for (int it = 0; it < 7; it++){
        int mt = wid + it * 8;
        if (mt < 49 && g < 3){
          int m0 = mt * 16;
          u16x4 wv;
          #pragma unroll
          for (int r = 0; r < 4; r++) wv[r] = f2b(accv[it][r]);
          *(u16x4*)(S + (n * MPITCH + 1 + m0 + col) * IPITCH + 4 * g) = wv;
        }
      }
    }
  }
  __syncthreads();

  for (int job = wid; job < 72; job += 8){
    int h = job % 12, row = job / 12;
    if (row < nvalid){
      float vals[13];
      float mx = -1e30f;
      #pragma unroll
      for (int tt = 0; tt < 13; tt++){
        int m = lane + 64 * tt;
        float v = -1e30f;
        if (m < NPIX) v = b2f(S[(row * MPITCH + 1 + m) * IPITCH + h]);
        vals[tt] = v;
        mx = fmaxf(mx, v);
      }
      #pragma unroll
      for (int o = 32; o > 0; o >>= 1) mx = fmaxf(mx, __shfl_xor(mx, o));
      float sum = 0.f;
      #pragma unroll
      for (int tt = 0; tt < 13; tt++){
        int m = lane + 64 * tt;
        float e = 0.f;
        if (m < NPIX) e = __expf(vals[tt] - mx);
        vals[tt] = e; sum += e;
      }
      #pragma unroll
      for (int o = 32; o > 0; o >>= 1) sum += __shfl_xor(sum, o);
      float inv = 1.f / sum;
      #pragma unroll
      for (int tt = 0; tt < 13; tt++){
        int m = lane + 64 * tt;
        if (m < NPIX) S[(row * MPITCH + 1 + m) * IPITCH + h] = f2b(vals[tt] * inv);
      }
    }
  }
  __syncthreads();

  u16x8 pfrag;
  #pragma unroll
  for (int jj = 0; jj < 8; jj++){
    int k = 8 * g + jj;
    pfrag[jj] = f2b((col < 12 && k < 12) ? Wrp[col * 12 + k] : 0.f);
  }
  float brpv[4];
  #pragma unroll
  for (int r = 0; r < 4; r++){ int o = 4 * g + r; brpv[r] = (o < 12) ? brp[o] : 0.f; }
  for (int job = wid; job < TQF * 49; job += 8){
    int row = job / 49, mt = job % 49;
    if (row < nvalid){
      int m0 = mt * 16;
      int base = (row * MPITCH + 1 + m0 + col) * IPITCH;
      u16x8 bf = ldfrag12(S, base, g);
      f32x4 d = mfma_bf16(pfrag, bf, (f32x4)0.f);
      u16x4 idv = *(const u16x4*)(S + base + 4 * g);
      float res[4];
      #pragma unroll
      for (int r = 0; r < 4; r++) res[r] = d[r] + b2f(idv[r]) + brpv[r];
      if (g < 3){
        u16x4 wv;
        #pragma unroll
        for (int r = 0; r < 4; r++) wv[r] = f2b(res[r]);
        *(u16x4*)(S + base + 4 * g) = wv;
      }
    }
  }
  __syncthreads();

  #pragma unroll
  for (int hi = 0; hi < 2; hi++){
    int h = wid + hi * 8;
    if (h < 12){
      f32x4 acc0 = (f32x4)0.f, acc1 = (f32x4)0.f;
      for (int ks = 0; ks < 25; ks++){
        int m0 = ks * 32;
        u16x8 af = (u16x8)0;
        if (col < TQF){
          #pragma unroll
          for (int jj = 0; jj < 8; jj++){
            int m = m0 + 8 * g + jj;
            if (m < NPIX) af[jj] = S[(col * MPITCH + 1 + m) * IPITCH + h];
          }
        }
        u16x8 bv0 = (u16x8)0, bv1 = (u16x8)0;
        if (m0 + 8 * g < NPIX){
          bv0 = *(const u16x8*)(Vt + ((b * 12 + h) * 32 + col) * NPIX + m0 + 8 * g);
          bv1 = *(const u16x8*)(Vt + ((b * 12 + h) * 32 + 16 + col) * NPIX + m0 + 8 * g);
        }
        acc0 = mfma_bf16(af, bv0, acc0);
        acc1 = mfma_bf16(af, bv1, acc1);
      }
      #pragma unroll
      for (int r = 0; r < 4; r++){
        int nloc = 4 * g + r;
        if (nloc < nvalid){
          int n = n0 + nloc;
          O[(b * NPIX + n) * CDIM + h * 32 + col] = f2b(acc0[r]);
          O[(b * NPIX + n) * CDIM + h * 32 + 16 + col] = f2b(acc1[r]);
        }
      }
    }
  }
}

// ---------------- K3: output projection ----------------
__global__ __launch_bounds__(256) void out_gemm(const u16* Wo_bf, const float* bo, const u16* O,
                                                float* out){
  int bid = blockIdx.x;
  int nt = bid % 7; int ot = (bid / 7) % 6; int b = bid / 42;
  int o0 = ot * 64, n0 = nt * 112;
  int lane = threadIdx.x & 63, w = threadIdx.x >> 6;
  int col = lane & 15, g = lane >> 4;
  int orow = o0 + w * 16;
  f32x4 acc[7];
  #pragma unroll
  for (int i = 0; i < 7; i++) acc[i] = (f32x4)0.f;
  for (int ks = 0; ks < 12; ks++){
    int c0 = ks * 32;
    u16x8 a = *(const u16x8*)(Wo_bf + (orow + col) * CDIM + c0 + 8 * g);
    #pragma unroll
    for (int t = 0; t < 7; t++){
      int n = n0 + t * 16 + col;
      u16x8 bb = *(const u16x8*)(O + (b * NPIX + n) * CDIM + c0 + 8 * g);
      acc[t] = mfma_bf16(a, bb, acc[t]);
    }
  }
  #pragma unroll
  for (int t = 0; t < 7; t++){
    int n = n0 + t * 16 + col;
    #pragma unroll
    for (int r = 0; r < 4; r++){
      int o = orow + 4 * g + r;
      out[(b * CDIM + o) * NPIX + n] = acc[t][r] + bo[o];
    }
  }
}

extern "C" void kernel_launch(void* const* d_in, const int* in_sizes, int n_in,
                              void* d_out, int out_size, void* d_ws, size_t ws_size,
                              hipStream_t stream){
  const float* x   = (const float*)d_in[0];
  const float* Wq  = (const float*)d_in[1];
  const float* bq  = (const float*)d_in[2];
  const float* Wkv = (const float*)d_in[3];
  const float* bkv = (const float*)d_in[4];
  const float* Wre = (const float*)d_in[5];
  const float* bre = (const float*)d_in[6];
  const float* Wrp = (const float*)d_in[7];
  const float* brp = (const float*)d_in[8];
  const float* rpb = (const float*)d_in[9];
  const float* Wo  = (const float*)d_in[10];
  const float* bo  = (const float*)d_in[11];
  const int*   rel = (const int*)d_in[12];
  float* out = (float*)d_out;
  char* ws = (char*)d_ws;

  const size_t o_Wall = 0;
  const size_t o_ball = 884736;
  const size_t o_Wo   = 889344;
  const size_t o_xT   = 1184256;
  const size_t o_bias = 10818048;
  const size_t o_Qs   = 25570048;
  const size_t o_Kb   = 35203840;
  const size_t o_Vt   = 44837632;
  const size_t o_O    = 54471424;
  const size_t o_zrow = 64105216;
  const size_t o_S    = 64124160;
  const size_t sperb  = (size_t)NPIX * SROW * 2;   // 14,789,376

  u16*  Wall  = (u16*)(ws + o_Wall);
  float* ball = (float*)(ws + o_ball);
  u16*  Wo_bf = (u16*)(ws + o_Wo);
  u16*  xT    = (u16*)(ws + o_xT);
  u16*  biasC = (u16*)(ws + o_bias);
  u16*  Qs    = (u16*)(ws + o_Qs);
  u16*  Kb    = (u16*)(ws + o_Kb);
  u16*  Vt    = (u16*)(ws + o_Vt);
  u16*  O     = (u16*)(ws + o_O);
  u16*  zrow  = (u16*)(ws + o_zrow);
  u16*  Sbuf  = (u16*)(ws + o_S);

  // G=8 keeps the steady-state working set (~182 MB) inside the 256 MB L3.
  int G = 8;
  while (G > 1 && o_S + (size_t)G * sperb + 64 > ws_size) G >>= 1;
  bool split = (o_S + (size_t)G * sperb + 64 <= ws_size);

  hipLaunchKernelGGL(prep_w, dim3((1152*384 + 384*384 + 1152 + 255) / 256), dim3(256), 0, stream,
                     Wq, bq, Wkv, bkv, Wo, Wall, ball, Wo_bf);
  hipLaunchKernelGGL(prep_xt, dim3(16 * 12 * 25), dim3(256), 0, stream, x, xT);
  hipLaunchKernelGGL(prep_bias, dim3((NPIX * NPIX + 255) / 256), dim3(256), 0, stream,
                     rel, rpb, bre, biasC);
  hipLaunchKernelGGL(qkv_gemm, dim3(16 * 18 * 7), dim3(256), 0, stream, Wall, ball, xT, Qs, Kb, Vt);

  if (split){
    hipLaunchKernelGGL(zfill, dim3((9448 + 511) / 512), dim3(512), 0, stream, zrow, 9448);
    const int ldsConv = TQ * LROW * 2;   // 37,696 B -> 4 blocks/CU
    hipFuncSetAttribute((const void*)conv_fused, hipFuncAttributeMaxDynamicSharedMemorySize, ldsConv);
    for (int b0 = 0; b0 < NBATCH; b0 += G){
      hipLaunchKernelGGL(s_gemm, dim3(G * 49), dim3(512), 0, stream, Qs, Kb, Sbuf, b0);
      hipLaunchKernelGGL(conv_fused, dim3(G * 392), dim3(512), ldsConv, stream,
                         Sbuf, zrow, biasC, Wre, Wrp, brp, Vt, O, b0);
    }
  } else {
    const int ldsBytes = (SLOTS * MPITCH * IPITCH + 16) * 2;
    hipFuncSetAttribute((const void*)attn_fused, hipFuncAttributeMaxDynamicSharedMemorySize, ldsBytes);
    hipLaunchKernelGGL(attn_fused, dim3(2096), dim3(512), ldsBytes, stream,
                       Qs, Kb, Vt, biasC, Wre, Wrp, brp, O);
  }

  hipLaunchKernelGGL(out_gemm, dim3(16 * 6 * 7), dim3(256), 0, stream, Wo_bf, bo, O, out);
}

// Round 9
// 635.243 us; speedup vs baseline: 1.4069x; 1.4069x over previous
//
#include <hip/hip_runtime.h>
#include <cstdio>

#define NHEAD 12
#define NPIX 784
#define NBATCH 16
#define CDIM 384
// fused (fallback) params
#define TQF 6
#define SLOTS 8
#define MPITCH 786
#define IPITCH 12
// split-path params
#define TQ 4          // query rows per conv block (75.4 KB LDS -> 2 blocks/CU; best measured)
#define SROW 9432     // S row stride in u16 (786*12)
#define LROW 9424     // LDS logits row pitch in u16
#define CW 8          // conv_fused waves per block (512 threads; >512 doesn't pack, round 7)

typedef __bf16 bf16x8 __attribute__((ext_vector_type(8)));
typedef float f32x4 __attribute__((ext_vector_type(4)));
typedef unsigned short u16;
typedef unsigned short u16x2 __attribute__((ext_vector_type(2)));
typedef unsigned short u16x4 __attribute__((ext_vector_type(4)));
typedef unsigned short u16x8 __attribute__((ext_vector_type(8)));

__device__ __forceinline__ float b2f(u16 u){
  unsigned int x = ((unsigned int)u) << 16;
  float f; __builtin_memcpy(&f, &x, 4); return f;
}
__device__ __forceinline__ u16 f2b(float f){
  unsigned int x; __builtin_memcpy(&x, &f, 4);
  unsigned int r = (x + 0x7FFFu + ((x >> 16) & 1u)) >> 16;
  return (u16)r;
}
__device__ __forceinline__ f32x4 mfma_bf16(u16x8 a, u16x8 b, f32x4 c){
  return __builtin_amdgcn_mfma_f32_16x16x32_bf16(
      __builtin_bit_cast(bf16x8, a), __builtin_bit_cast(bf16x8, b), c, 0, 0, 0);
}
__device__ __forceinline__ u16x8 ldfrag12(const u16* S, int base, int g){
  u16x8 r = (u16x8)0;
  if (g == 0){
    u16x4 lo = *(const u16x4*)(S + base);
    u16x4 hi = *(const u16x4*)(S + base + 4);
    r[0]=lo[0]; r[1]=lo[1]; r[2]=lo[2]; r[3]=lo[3];
    r[4]=hi[0]; r[5]=hi[1]; r[6]=hi[2]; r[7]=hi[3];
  } else if (g == 1){
    u16x4 lo = *(const u16x4*)(S + base + 8);
    r[0]=lo[0]; r[1]=lo[1]; r[2]=lo[2]; r[3]=lo[3];
  }
  return r;
}

// ---------------- prep: weights ----------------
__global__ void prep_w(const float* Wq, const float* bq, const float* Wkv, const float* bkv,
                       const float* Wo, u16* Wall, float* ball, u16* Wo_bf){
  int idx = blockIdx.x * 256 + threadIdx.x;
  const float scale = 0.17677669529663687f; // 1/sqrt(32)
  const int t1 = 1152 * 384;
  if (idx < t1){
    float v = (idx < 384*384) ? Wq[idx] * scale : Wkv[idx - 384*384];
    Wall[idx] = f2b(v);
  } else if (idx < t1 + 384*384){
    Wo_bf[idx - t1] = f2b(Wo[idx - t1]);
  } else if (idx < t1 + 384*384 + 1152){
    int o = idx - t1 - 384*384;
    ball[o] = (o < 384) ? bq[o] * scale : bkv[o - 384];
  }
}

__global__ void zfill(u16* p, int n){
  int idx = blockIdx.x * 512 + threadIdx.x;
  if (idx < n) p[idx] = 0;
}

// ---------------- prep: x transpose to [b][n][c] bf16 ----------------
__global__ void prep_xt(const float* x, u16* xT){
  __shared__ float tile[32][33];
  int bid = blockIdx.x;
  int nt = bid % 25; int ct = (bid / 25) % 12; int b = bid / (25 * 12);
  int n0 = nt * 32, c0 = ct * 32;
  int lt = threadIdx.x;
  int ln = lt & 31, lr = lt >> 5;
  #pragma unroll
  for (int k = 0; k < 4; k++){
    int c = lr + k * 8;
    int n = n0 + ln;
    float v = (n < NPIX) ? x[(b * CDIM + c0 + c) * NPIX + n] : 0.f;
    tile[c][ln] = v;
  }
  __syncthreads();
  #pragma unroll
  for (int k = 0; k < 4; k++){
    int wn = lr + k * 8;
    int n = n0 + wn;
    if (n < NPIX) xT[(b * NPIX + n) * CDIM + c0 + ln] = f2b(tile[ln][wn]);
  }
}

// ---------------- prep: bias table [n][m][12] = rpb[rel]+bre ----------------
__global__ void prep_bias(const int* rel, const float* rpb, const float* bre, u16* biasC){
  int idx = blockIdx.x * 256 + threadIdx.x;
  if (idx >= NPIX * NPIX) return;
  int ri = rel[idx];
  u16x4 v[3];
  #pragma unroll
  for (int h = 0; h < 12; h++){
    float val = rpb[ri * 12 + h] + bre[h];
    v[h >> 2][h & 3] = f2b(val);
  }
  u16x4* dst = (u16x4*)(biasC + idx * 12);
  dst[0] = v[0]; dst[1] = v[1]; dst[2] = v[2];
}

// ---------------- K1: QKV projection GEMM ----------------
__global__ __launch_bounds__(256) void qkv_gemm(const u16* Wall, const float* ball, const u16* xT,
                                                u16* Qs, u16* Kb, u16* Vt){
  int bid = blockIdx.x;
  int nt = bid % 7; int ot = (bid / 7) % 18; int b = bid / 126;
  int o0 = ot * 64, n0 = nt * 112;
  int lane = threadIdx.x & 63, w = threadIdx.x >> 6;
  int col = lane & 15, g = lane >> 4;
  int orow = o0 + w * 16;
  f32x4 acc[7];
  #pragma unroll
  for (int i = 0; i < 7; i++) acc[i] = (f32x4)0.f;
  for (int ks = 0; ks < 12; ks++){
    int c0 = ks * 32;
    u16x8 a = *(const u16x8*)(Wall + (orow + col) * CDIM + c0 + 8 * g);
    #pragma unroll
    for (int t = 0; t < 7; t++){
      int n = n0 + t * 16 + col;
      u16x8 bb = *(const u16x8*)(xT + (b * NPIX + n) * CDIM + c0 + 8 * g);
      acc[t] = mfma_bf16(a, bb, acc[t]);
    }
  }
  #pragma unroll
  for (int t = 0; t < 7; t++){
    int n = n0 + t * 16 + col;
    #pragma unroll
    for (int r = 0; r < 4; r++){
      int o = orow + 4 * g + r;
      u16 hv = f2b(acc[t][r] + ball[o]);
      if (o < 384){
        int h = o >> 5, d = o & 31;
        Qs[((b * 12 + h) * NPIX + n) * 32 + d] = hv;
      } else if (o < 768){
        int oo = o - 384; int h = oo >> 5, d = oo & 31;
        Kb[((b * 12 + h) * NPIX + n) * 32 + d] = hv;
      } else {
        int oo = o - 768; int h = oo >> 5, d = oo & 31;
        Vt[((b * 12 + h) * 32 + d) * NPIX + n] = hv;
      }
    }
  }
}

// ---------------- K2a: S = Q K^T, layout [bg][n][786][12] bf16 (m padded +-1) ----------------
// XCD swizzle: bg = bid % G -> all blocks of one batch land on one XCD (Q/K panels L2-resident)
__global__ __launch_bounds__(512) void s_gemm(const u16* Qs, const u16* Kb, u16* S, int b0, int G){
  int bid = blockIdx.x;
  int bg = bid % G; int nt = bid / G;
  int b = b0 + bg;
  int n0 = nt * 16;
  int tid = threadIdx.x;
  int lane = tid & 63, wid = tid >> 6;
  int col = lane & 15, g = lane >> 4;
  u16* Sb = S + (size_t)bg * NPIX * SROW;
  // zero pad columns mp=0 and mp=785 for this n-strip
  for (int idx = tid; idx < 16 * 24; idx += 512){
    int r = idx / 24, c = idx % 24;
    int mp = (c < 12) ? 0 : 785;
    Sb[(size_t)(n0 + r) * SROW + mp * 12 + (c % 12)] = 0;
  }
  // hoist the 12 Q fragments (independent of mt)
  u16x8 af[12];
  #pragma unroll
  for (int h = 0; h < 12; h++)
    af[h] = *(const u16x8*)(Qs + ((size_t)(b * 12 + h) * NPIX + n0 + col) * 32 + 8 * g);
  for (int mt = wid; mt < 49; mt += 8){
    int m0 = mt * 16;
    u16x4 res[4][3];   // [r][word-of-3 u16x4] = 12 heads per (n,m)
    #pragma unroll
    for (int h = 0; h < 12; h++){
      u16x8 bb = *(const u16x8*)(Kb + ((size_t)(b * 12 + h) * NPIX + m0 + col) * 32 + 8 * g);
      f32x4 acc = mfma_bf16(af[h], bb, (f32x4)0.f);
      #pragma unroll
      for (int r = 0; r < 4; r++) res[r][h >> 2][h & 3] = f2b(acc[r]);
    }
    #pragma unroll
    for (int r = 0; r < 4; r++){
      size_t base = (size_t)(n0 + 4 * g + r) * SROW + (size_t)(1 + m0 + col) * 12;
      *(u16x4*)(Sb + base)     = res[r][0];
      *(u16x4*)(Sb + base + 4) = res[r][1];
      *(u16x4*)(Sb + base + 8) = res[r][2];
    }
  }
}

// ---------------- K2b: conv+bias+softmax+headmix+PV, logits-only LDS ----------------
// XCD swizzle: bg = bid % G -> each XCD owns one batch (V panel + halo S rows L2-resident)
__global__ __launch_bounds__(512, 4) void conv_fused(const u16* S, const u16* zrow,
        const u16* biasC, const float* Wre, const float* Wrp, const float* brp,
        const u16* Vt, u16* O, int b0, int G){
  extern __shared__ u16 L[];   // [TQ][LROW]
  int bid = blockIdx.x;
  int bg = bid % G; int nt = bid / G;
  int b = b0 + bg;
  int n0 = nt * TQ;
  int tid = threadIdx.x;
  int lane = tid & 63, wid = tid >> 6;
  int col = lane & 15, g = lane >> 4;
  const u16* Sb = S + (size_t)bg * NPIX * SROW;

  // conv weight fragments (2-tap K=24 pack: wf1: k<12 -> dx=0, k in [12,24) -> dx=1; wf2: k<12 -> dx=2)
  u16x8 wf1[3], wf2[3];
  #pragma unroll
  for (int dy = 0; dy < 3; dy++){
    u16x8 f1 = (u16x8)0, f2 = (u16x8)0;
    #pragma unroll
    for (int jj = 0; jj < 8; jj++){
      int k = 8 * g + jj;
      float v1 = 0.f, v2 = 0.f;
      if (col < 12){
        if (k < 12){
          v1 = Wre[((col * 12 + k) * 3 + dy) * 3 + 0];
          v2 = Wre[((col * 12 + k) * 3 + dy) * 3 + 2];
        } else if (k < 24){
          int i = k - 12;
          v1 = Wre[((col * 12 + i) * 3 + dy) * 3 + 1];
        }
      }
      f1[jj] = f2b(v1); f2[jj] = f2b(v2);
    }
    wf1[dy] = f1; wf2[dy] = f2;
  }

  // phase 1: conv + identity + bias -> logits in LDS, with 6-row reuse per m-tile
  for (int mt = wid; mt < 49; mt += CW){
    int m0 = mt * 16;
    const u16* rp[6];
    #pragma unroll
    for (int rr = 0; rr < 6; rr++){
      int r = n0 - 1 + rr;
      rp[rr] = (r >= 0 && r < NPIX) ? Sb + (size_t)r * SROW : zrow;
    }
    u16x8 fA[6], fB[6];
    #pragma unroll
    for (int rr = 0; rr < 6; rr++){
      fA[rr] = (g < 3) ? *(const u16x8*)(rp[rr] + (m0 + col) * 12 + 8 * g) : (u16x8)0;
      fB[rr] = (g < 2) ? *(const u16x8*)(rp[rr] + (m0 + col + 2) * 12 + 8 * g) : (u16x8)0;
    }
    f32x4 acc[4];
    #pragma unroll
    for (int n = 0; n < 4; n++) acc[n] = (f32x4)0.f;
    #pragma unroll
    for (int dy = 0; dy < 3; dy++){
      #pragma unroll
      for (int n = 0; n < 4; n++){
        acc[n] = mfma_bf16(wf1[dy], fA[n + dy], acc[n]);
        acc[n] = mfma_bf16(wf2[dy], fB[n + dy], acc[n]);
      }
    }
    if (g < 3){
      #pragma unroll
      for (int n = 0; n < 4; n++){
        u16x4 idv = *(const u16x4*)(rp[n + 1] + (m0 + col + 1) * 12 + 4 * g);
        u16x4 bv  = *(const u16x4*)(biasC + ((size_t)(n0 + n) * NPIX + m0 + col) * 12 + 4 * g);
        u16x4 wv;
        #pragma unroll
        for (int r = 0; r < 4; r++) wv[r] = f2b(acc[n][r] + b2f(idv[r]) + b2f(bv[r]));
        *(u16x4*)(L + n * LROW + (m0 + col) * 12 + 4 * g) = wv;
      }
    }
  }
  __syncthreads();

  // phase 2: softmax per row, 2 heads per job (24 jobs -> 3/wave, balanced)
  for (int job = wid; job < TQ * 6; job += CW){
    int row = job / 6, hg = job % 6;
    float v0[13], v1[13];
    float mx0 = -1e30f, mx1 = -1e30f;
    #pragma unroll
    for (int tt = 0; tt < 13; tt++){
      int m = lane + 64 * tt;
      float a = -1e30f, bb = -1e30f;
      if (m < NPIX){
        u16x2 lv = *(const u16x2*)(L + row * LROW + m * 12 + 2 * hg);
        a = b2f(lv[0]); bb = b2f(lv[1]);
      }
      v0[tt] = a; v1[tt] = bb;
      mx0 = fmaxf(mx0, a); mx1 = fmaxf(mx1, bb);
    }
    #pragma unroll
    for (int o = 32; o > 0; o >>= 1){
      mx0 = fmaxf(mx0, __shfl_xor(mx0, o));
      mx1 = fmaxf(mx1, __shfl_xor(mx1, o));
    }
    float s0 = 0.f, s1 = 0.f;
    #pragma unroll
    for (int tt = 0; tt < 13; tt++){
      int m = lane + 64 * tt;
      float e0 = 0.f, e1 = 0.f;
      if (m < NPIX){
        e0 = __expf(v0[tt] - mx0);
        e1 = __expf(v1[tt] - mx1);
      }
      v0[tt] = e0; v1[tt] = e1;
      s0 += e0; s1 += e1;
    }
    #pragma unroll
    for (int o = 32; o > 0; o >>= 1){
      s0 += __shfl_xor(s0, o);
      s1 += __shfl_xor(s1, o);
    }
    float i0 = 1.f / s0, i1 = 1.f / s1;
    #pragma unroll
    for (int tt = 0; tt < 13; tt++){
      int m = lane + 64 * tt;
      if (m < NPIX){
        u16x2 wv; wv[0] = f2b(v0[tt] * i0); wv[1] = f2b(v1[tt] * i1);
        *(u16x2*)(L + row * LROW + m * 12 + 2 * hg) = wv;
      }
    }
  }
  __syncthreads();

  // phase 3: P' = P + Wrp@P + brp, in place (exact f32 identity add)
  u16x8 pfrag = (u16x8)0;
  #pragma unroll
  for (int jj = 0; jj < 8; jj++){
    int k = 8 * g + jj;
    pfrag[jj] = f2b((col < 12 && k < 12) ? Wrp[col * 12 + k] : 0.f);
  }
  float brpv[4];
  #pragma unroll
  for (int r = 0; r < 4; r++){ int o = 4 * g + r; brpv[r] = (o < 12) ? brp[o] : 0.f; }
  for (int job = wid; job < TQ * 49; job += CW){
    int row = job / 49, mt = job % 49;
    int m0 = mt * 16;
    int base = row * LROW + (m0 + col) * 12;
    u16x8 bf = ldfrag12(L, base, g);
    f32x4 d = mfma_bf16(pfrag, bf, (f32x4)0.f);
    u16x4 idv = *(const u16x4*)(L + base + 4 * g);
    if (g < 3){
      u16x4 wv;
      #pragma unroll
      for (int r = 0; r < 4; r++) wv[r] = f2b(d[r] + b2f(idv[r]) + brpv[r]);
      *(u16x4*)(L + base + 4 * g) = wv;
    }
  }
  __syncthreads();

  // phase 4: PV -> O[b][n][h*32+d]; ks unrolled x2, dual accumulators (reassoc OK)
  for (int job = wid; job < 12; job += CW){
    int h = job;
    f32x4 a0A = (f32x4)0.f, a1A = (f32x4)0.f;
    f32x4 a0B = (f32x4)0.f, a1B = (f32x4)0.f;
    const u16* vrow0 = Vt + ((size_t)(b * 12 + h) * 32 + col) * NPIX;
    const u16* vrow1 = Vt + ((size_t)(b * 12 + h) * 32 + 16 + col) * NPIX;
    for (int ks = 0; ks < 24; ks += 2){
      int m0 = ks * 32;
      u16x8 af0 = (u16x8)0, af1 = (u16x8)0;
      if (col < TQ){
        #pragma unroll
        for (int jj = 0; jj < 8; jj++){
          af0[jj] = L[col * LROW + (m0 + 8 * g + jj) * 12 + h];
          af1[jj] = L[col * LROW + (m0 + 32 + 8 * g + jj) * 12 + h];
        }
      }
      u16x8 b00 = *(const u16x8*)(vrow0 + m0 + 8 * g);
      u16x8 b01 = *(const u16x8*)(vrow1 + m0 + 8 * g);
      u16x8 b10 = *(const u16x8*)(vrow0 + m0 + 32 + 8 * g);
      u16x8 b11 = *(const u16x8*)(vrow1 + m0 + 32 + 8 * g);
      a0A = mfma_bf16(af0, b00, a0A);
      a1A = mfma_bf16(af0, b01, a1A);
      a0B = mfma_bf16(af1, b10, a0B);
      a1B = mfma_bf16(af1, b11, a1B);
    }
    { // tail ks = 24 (m0 = 768)
      int m0 = 768;
      u16x8 af0 = (u16x8)0;
      if (col < TQ){
        #pragma unroll
        for (int jj = 0; jj < 8; jj++){
          int m = m0 + 8 * g + jj;
          if (m < NPIX) af0[jj] = L[col * LROW + m * 12 + h];
        }
      }
      u16x8 b00 = (u16x8)0, b01 = (u16x8)0;
      if (m0 + 8 * g < NPIX){
        b00 = *(const u16x8*)(vrow0 + m0 + 8 * g);
        b01 = *(const u16x8*)(vrow1 + m0 + 8 * g);
      }
      a0A = mfma_bf16(af0, b00, a0A);
      a1A = mfma_bf16(af0, b01, a1A);
    }
    f32x4 acc0, acc1;
    #pragma unroll
    for (int r = 0; r < 4; r++){ acc0[r] = a0A[r] + a0B[r]; acc1[r] = a1A[r] + a1B[r]; }
    if (g == 0){
      size_t ob = (size_t)(b * NPIX + n0) * CDIM + h * 32 + col;
      #pragma unroll
      for (int r = 0; r < 4; r++){
        O[ob + (size_t)r * CDIM]      = f2b(acc0[r]);
        O[ob + (size_t)r * CDIM + 16] = f2b(acc1[r]);
      }
    }
  }
}

// ---------------- fallback fused kernel (round-1, proven) ----------------
__global__ __launch_bounds__(512) void attn_fused(const u16* Qs, const u16* Kb, const u16* Vt,
        const u16* biasC, const float* Wre, const float* Wrp, const float* brp, u16* O){
  extern __shared__ u16 S[];
  int j = blockIdx.x;
  int rb = j & 7, q = j >> 3;
  int b = rb + 8 * (q & 1);
  int t = q >> 1;
  int n0 = t * TQF;
  int nvalid = min(TQF, NPIX - n0);
  int tid = threadIdx.x;
  int lane = tid & 63, wid = tid >> 6;
  int col = lane & 15, g = lane >> 4;

  for (int idx = tid; idx < SLOTS * 2 * 12; idx += 512){
    int slot = idx / 24; int rem = idx % 24; int cs = rem / 12; int i = rem % 12;
    int mcol = cs ? (MPITCH - 1) : 0;
    S[(slot * MPITCH + mcol) * IPITCH + i] = 0;
  }
  if (tid < 16) S[SLOTS * MPITCH * IPITCH + tid] = 0;
  __syncthreads();

  for (int job = wid; job < 147; job += 8){
    int hg = job / 49, mt = job % 49;
    int h0 = hg * 4, m0 = mt * 16;
    f32x4 acc[4];
    #pragma unroll
    for (int hh = 0; hh < 4; hh++){
      int h = h0 + hh;
      u16x8 a = *(const u16x8*)(Kb + ((b * 12 + h) * NPIX + m0 + col) * 32 + 8 * g);
      int nn = n0 - 1 + col;
      u16x8 bb = (u16x8)0;
      if (col < 8 && nn >= 0 && nn < NPIX)
        bb = *(const u16x8*)(Qs + ((b * 12 + h) * NPIX + nn) * 32 + 8 * g);
      acc[hh] = mfma_bf16(a, bb, (f32x4)0.f);
    }
    if (col < 8){
      #pragma unroll
      for (int r = 0; r < 4; r++){
        int m = m0 + 4 * g + r;
        u16x4 wv;
        #pragma unroll
        for (int hh = 0; hh < 4; hh++) wv[hh] = f2b(acc[hh][r]);
        *(u16x4*)(S + (col * MPITCH + 1 + m) * IPITCH + h0) = wv;
      }
    }
  }
  __syncthreads();

  u16x8 wfrag[9];
  #pragma unroll
  for (int dy = 0; dy < 3; dy++)
  #pragma unroll
  for (int dx = 0; dx < 3; dx++){
    u16x8 f;
    #pragma unroll
    for (int jj = 0; jj < 8; jj++){
      int k = 8 * g + jj;
      float v = (col < 12 && k < 12) ? Wre[(col * 12 + k) * 9 + dy * 3 + dx] : 0.f;
      f[jj] = f2b(v);
    }
    wfrag[dy * 3 + dx] = f;
  }

  for (int n = 0; n < TQF; n++){
    bool rv = (n < nvalid);
    int ngl = n0 + n;
    f32x4 accv[7];
    if (rv){
      #pragma unroll
      for (int it = 0; it < 7; it++){
        int mt = wid + it * 8;
        if (mt < 49){
          int m0 = mt * 16;
          f32x4 a = (f32x4)0.f;
          #pragma unroll
          for (int dy = 0; dy < 3; dy++){
            int slot = n + dy;
            #pragma unroll
            for (int dx = 0; dx < 3; dx++){
              int base = (slot * MPITCH + (m0 + col + dx)) * IPITCH;
              u16x8 bf = ldfrag12(S, base, g);
              a = mfma_bf16(wfrag[dy * 3 + dx], bf, a);
            }
          }
          u16x4 idv = *(const u16x4*)(S + ((n + 1) * MPITCH + 1 + m0 + col) * IPITCH + 4 * g);
          u16x4 bv  = *(const u16x4*)(biasC + (ngl * NPIX + m0 + col) * 12 + 4 * g);
          f32x4 res;
          #pragma unroll
          for (int r = 0; r < 4; r++) res[r] = a[r] + b2f(idv[r]) + b2f(bv[r]);
          accv[it] = res;
        }
      }
    }
    __syncthreads();
    if (rv){
      #pragma unroll
      for (int it = 0; it < 7; it++){
        int mt = wid + it * 8;
        if (mt < 49 && g < 3){
          int m0 = mt * 16;
          u16x4 wv;
          #pragma unroll
          for (int r = 0; r < 4; r++) wv[r] = f2b(accv[it][r]);
          *(u16x4*)(S + (n * MPITCH + 1 + m0 + col) * IPITCH + 4 * g) = wv;
        }
      }
    }
  }
  __syncthreads();

  for (int job = wid; job < 72; job += 8){
    int h = job % 12, row = job / 12;
    if (row < nvalid){
      float vals[13];
      float mx = -1e30f;
      #pragma unroll
      for (int tt = 0; tt < 13; tt++){
        int m = lane + 64 * tt;
        float v = -1e30f;
        if (m < NPIX) v = b2f(S[(row * MPITCH + 1 + m) * IPITCH + h]);
        vals[tt] = v;
        mx = fmaxf(mx, v);
      }
      #pragma unroll
      for (int o = 32; o > 0; o >>= 1) mx = fmaxf(mx, __shfl_xor(mx, o));
      float sum = 0.f;
      #pragma unroll
      for (int tt = 0; tt < 13; tt++){
        int m = lane + 64 * tt;
        float e = 0.f;
        if (m < NPIX) e = __expf(vals[tt] - mx);
        vals[tt] = e; sum += e;
      }
      #pragma unroll
      for (int o = 32; o > 0; o >>= 1) sum += __shfl_xor(sum, o);
      float inv = 1.f / sum;
      #pragma unroll
      for (int tt = 0; tt < 13; tt++){
        int m = lane + 64 * tt;
        if (m < NPIX) S[(row * MPITCH + 1 + m) * IPITCH + h] = f2b(vals[tt] * inv);
      }
    }
  }
  __syncthreads();

  u16x8 pfrag;
  #pragma unroll
  for (int jj = 0; jj < 8; jj++){
    int k = 8 * g + jj;
    pfrag[jj] = f2b((col < 12 && k < 12) ? Wrp[col * 12 + k] : 0.f);
  }
  float brpv[4];
  #pragma unroll
  for (int r = 0; r < 4; r++){ int o = 4 * g + r; brpv[r] = (o < 12) ? brp[o] : 0.f; }
  for (int job = wid; job < TQF * 49; job += 8){
    int row = job / 49, mt = job % 49;
    if (row < nvalid){
      int m0 = mt * 16;
      int base = (row * MPITCH + 1 + m0 + col) * IPITCH;
      u16x8 bf = ldfrag12(S, base, g);
      f32x4 d = mfma_bf16(pfrag, bf, (f32x4)0.f);
      u16x4 idv = *(const u16x4*)(S + base + 4 * g);
      float res[4];
      #pragma unroll
      for (int r = 0; r < 4; r++) res[r] = d[r] + b2f(idv[r]) + brpv[r];
      if (g < 3){
        u16x4 wv;
        #pragma unroll
        for (int r = 0; r < 4; r++) wv[r] = f2b(res[r]);
        *(u16x4*)(S + base + 4 * g) = wv;
      }
    }
  }
  __syncthreads();

  #pragma unroll
  for (int hi = 0; hi < 2; hi++){
    int h = wid + hi * 8;
    if (h < 12){
      f32x4 acc0 = (f32x4)0.f, acc1 = (f32x4)0.f;
      for (int ks = 0; ks < 25; ks++){
        int m0 = ks * 32;
        u16x8 af = (u16x8)0;
        if (col < TQF){
          #pragma unroll
          for (int jj = 0; jj < 8; jj++){
            int m = m0 + 8 * g + jj;
            if (m < NPIX) af[jj] = S[(col * MPITCH + 1 + m) * IPITCH + h];
          }
        }
        u16x8 bv0 = (u16x8)0, bv1 = (u16x8)0;
        if (m0 + 8 * g < NPIX){
          bv0 = *(const u16x8*)(Vt + ((b * 12 + h) * 32 + col) * NPIX + m0 + 8 * g);
          bv1 = *(const u16x8*)(Vt + ((b * 12 + h) * 32 + 16 + col) * NPIX + m0 + 8 * g);
        }
        acc0 = mfma_bf16(af, bv0, acc0);
        acc1 = mfma_bf16(af, bv1, acc1);
      }
      #pragma unroll
      for (int r = 0; r < 4; r++){
        int nloc = 4 * g + r;
        if (nloc < nvalid){
          int n = n0 + nloc;
          O[(b * NPIX + n) * CDIM + h * 32 + col] = f2b(acc0[r]);
          O[(b * NPIX + n) * CDIM + h * 32 + 16 + col] = f2b(acc1[r]);
        }
      }
    }
  }
}

// ---------------- K3: output projection ----------------
__global__ __launch_bounds__(256) void out_gemm(const u16* Wo_bf, const float* bo, const u16* O,
                                                float* out){
  int bid = blockIdx.x;
  int nt = bid % 7; int ot = (bid / 7) % 6; int b = bid / 42;
  int o0 = ot * 64, n0 = nt * 112;
  int lane = threadIdx.x & 63, w = threadIdx.x >> 6;
  int col = lane & 15, g = lane >> 4;
  int orow = o0 + w * 16;
  f32x4 acc[7];
  #pragma unroll
  for (int i = 0; i < 7; i++) acc[i] = (f32x4)0.f;
  for (int ks = 0; ks < 12; ks++){
    int c0 = ks * 32;
    u16x8 a = *(const u16x8*)(Wo_bf + (orow + col) * CDIM + c0 + 8 * g);
    #pragma unroll
    for (int t = 0; t < 7; t++){
      int n = n0 + t * 16 + col;
      u16x8 bb = *(const u16x8*)(O + (b * NPIX + n) * CDIM + c0 + 8 * g);
      acc[t] = mfma_bf16(a, bb, acc[t]);
    }
  }
  #pragma unroll
  for (int t = 0; t < 7; t++){
    int n = n0 + t * 16 + col;
    #pragma unroll
    for (int r = 0; r < 4; r++){
      int o = orow + 4 * g + r;
      out[(b * CDIM + o) * NPIX + n] = acc[t][r] + bo[o];
    }
  }
}

extern "C" void kernel_launch(void* const* d_in, const int* in_sizes, int n_in,
                              void* d_out, int out_size, void* d_ws, size_t ws_size,
                              hipStream_t stream){
  const float* x   = (const float*)d_in[0];
  const float* Wq  = (const float*)d_in[1];
  const float* bq  = (const float*)d_in[2];
  const float* Wkv = (const float*)d_in[3];
  const float* bkv = (const float*)d_in[4];
  const float* Wre = (const float*)d_in[5];
  const float* bre = (const float*)d_in[6];
  const float* Wrp = (const float*)d_in[7];
  const float* brp = (const float*)d_in[8];
  const float* rpb = (const float*)d_in[9];
  const float* Wo  = (const float*)d_in[10];
  const float* bo  = (const float*)d_in[11];
  const int*   rel = (const int*)d_in[12];
  float* out = (float*)d_out;
  char* ws = (char*)d_ws;

  const size_t o_Wall = 0;
  const size_t o_ball = 884736;
  const size_t o_Wo   = 889344;
  const size_t o_xT   = 1184256;
  const size_t o_bias = 10818048;
  const size_t o_Qs   = 25570048;
  const size_t o_Kb   = 35203840;
  const size_t o_Vt   = 44837632;
  const size_t o_O    = 54471424;
  const size_t o_zrow = 64105216;
  const size_t o_S    = 64124160;
  const size_t sperb  = (size_t)NPIX * SROW * 2;   // 14,789,376

  u16*  Wall  = (u16*)(ws + o_Wall);
  float* ball = (float*)(ws + o_ball);
  u16*  Wo_bf = (u16*)(ws + o_Wo);
  u16*  xT    = (u16*)(ws + o_xT);
  u16*  biasC = (u16*)(ws + o_bias);
  u16*  Qs    = (u16*)(ws + o_Qs);
  u16*  Kb    = (u16*)(ws + o_Kb);
  u16*  Vt    = (u16*)(ws + o_Vt);
  u16*  O     = (u16*)(ws + o_O);
  u16*  zrow  = (u16*)(ws + o_zrow);
  u16*  Sbuf  = (u16*)(ws + o_S);

  // G=8 keeps the steady-state working set (~182 MB) inside the 256 MB L3.
  int G = 8;
  while (G > 1 && o_S + (size_t)G * sperb + 64 > ws_size) G >>= 1;
  bool split = (o_S + (size_t)G * sperb + 64 <= ws_size);

  hipLaunchKernelGGL(prep_w, dim3((1152*384 + 384*384 + 1152 + 255) / 256), dim3(256), 0, stream,
                     Wq, bq, Wkv, bkv, Wo, Wall, ball, Wo_bf);
  hipLaunchKernelGGL(prep_xt, dim3(16 * 12 * 25), dim3(256), 0, stream, x, xT);
  hipLaunchKernelGGL(prep_bias, dim3((NPIX * NPIX + 255) / 256), dim3(256), 0, stream,
                     rel, rpb, bre, biasC);
  hipLaunchKernelGGL(qkv_gemm, dim3(16 * 18 * 7), dim3(256), 0, stream, Wall, ball, xT, Qs, Kb, Vt);

  if (split){
    hipLaunchKernelGGL(zfill, dim3((9448 + 511) / 512), dim3(512), 0, stream, zrow, 9448);
    const int ldsConv = TQ * LROW * 2;   // 75,392 B -> 2 blocks/CU
    hipFuncSetAttribute((const void*)conv_fused, hipFuncAttributeMaxDynamicSharedMemorySize, ldsConv);
    for (int b0 = 0; b0 < NBATCH; b0 += G){
      hipLaunchKernelGGL(s_gemm, dim3(G * 49), dim3(512), 0, stream, Qs, Kb, Sbuf, b0, G);
      hipLaunchKernelGGL(conv_fused, dim3(G * 196), dim3(512), ldsConv, stream,
                         Sbuf, zrow, biasC, Wre, Wrp, brp, Vt, O, b0, G);
    }
  } else {
    const int ldsBytes = (SLOTS * MPITCH * IPITCH + 16) * 2;
    hipFuncSetAttribute((const void*)attn_fused, hipFuncAttributeMaxDynamicSharedMemorySize, ldsBytes);
    hipLaunchKernelGGL(attn_fused, dim3(2096), dim3(512), ldsBytes, stream,
                       Qs, Kb, Vt, biasC, Wre, Wrp, brp, O);
  }

  hipLaunchKernelGGL(out_gemm, dim3(16 * 6 * 7), dim3(256), 0, stream, Wo_bf, bo, O, out);
}